// Round 13
// baseline (278.919 us; speedup 1.0000x reference)
//
#include <hip/hip_runtime.h>
#include <hip/hip_fp16.h>

#define NN 100000
#define NE 1600000
#define HH 64
#define BSH 8                 // 256 nodes per bucket
#define NBUK 391              // ceil(NN / 256)

typedef unsigned long long u64;

// packed edge record: src[16:0] | dst[33:17] | eid[54:34]
__device__ __forceinline__ u64 epack(int s, int d, int e) {
    return (u64)(unsigned)s | ((u64)(unsigned)d << 17) | ((u64)(unsigned)e << 34);
}
__device__ __forceinline__ int esrc(u64 w) { return (int)(w & 0x1FFFF); }
__device__ __forceinline__ int edst(u64 w) { return (int)((w >> 17) & 0x1FFFF); }
__device__ __forceinline__ int eeid(u64 w) { return (int)(w >> 34); }

// ---------------- bucket histogram (per-block LDS, NBUK global atomics/block) -------

__global__ __launch_bounds__(512) void k_bhist(const int* __restrict__ dst,
                                               int* __restrict__ bcnt) {
    __shared__ int cnt[NBUK];
    int tid = threadIdx.x;
    for (int t = tid; t < NBUK; t += 512) cnt[t] = 0;
    __syncthreads();
    int e0 = blockIdx.x * 2048 + tid;
    #pragma unroll
    for (int i = 0; i < 4; ++i) {
        int e = e0 + i * 512;
        if (e < NE) atomicAdd(&cnt[dst[e] >> BSH], 1);
    }
    __syncthreads();
    for (int t = tid; t < NBUK; t += 512)
        if (cnt[t] > 0) atomicAdd(&bcnt[t], cnt[t]);
}

// ---------------- bucket scan: NBUK -> bases + partA cursors (1 block) --------------

__global__ __launch_bounds__(512) void k_bscan(const int* __restrict__ bcnt,
                                               int* __restrict__ bbase,
                                               int* __restrict__ bcur) {
    __shared__ int sh[512];
    int tid = threadIdx.x;
    int v = (tid < NBUK) ? bcnt[tid] : 0;
    sh[tid] = v;
    __syncthreads();
    for (int off = 1; off < 512; off <<= 1) {
        int t = (tid >= off) ? sh[tid - off] : 0;
        __syncthreads();
        sh[tid] += t;
        __syncthreads();
    }
    if (tid < NBUK) {
        int ex = sh[tid] - v;
        bbase[tid] = ex;
        bcur[tid] = ex;
    }
    if (tid == 0) bbase[NBUK] = NE;
}

// ---------------- pass A: partition edges into 256-node dst-buckets ----------------
// 782 blocks x 512 threads (2048 edges each) for occupancy; per-block LDS histogram
// -> one chunk reservation per (block,bucket) -> chunked scatter (L2-merged).

__global__ __launch_bounds__(512) void k_partA(const int* __restrict__ src,
                                               const int* __restrict__ dst,
                                               int* __restrict__ bcur,
                                               u64* __restrict__ partA) {
    __shared__ int cnt[NBUK], off[NBUK], base[NBUK];
    int tid = threadIdx.x;
    for (int t = tid; t < NBUK; t += 512) { cnt[t] = 0; off[t] = 0; }
    __syncthreads();
    int e0 = blockIdx.x * 2048 + tid;
    int d0 = 0, d1 = 0, d2 = 0, d3 = 0;
    if (e0 < NE)           { d0 = dst[e0];           atomicAdd(&cnt[d0 >> BSH], 1); }
    if (e0 + 512 < NE)     { d1 = dst[e0 + 512];     atomicAdd(&cnt[d1 >> BSH], 1); }
    if (e0 + 1024 < NE)    { d2 = dst[e0 + 1024];    atomicAdd(&cnt[d2 >> BSH], 1); }
    if (e0 + 1536 < NE)    { d3 = dst[e0 + 1536];    atomicAdd(&cnt[d3 >> BSH], 1); }
    __syncthreads();
    for (int t = tid; t < NBUK; t += 512)
        if (cnt[t] > 0) base[t] = atomicAdd(&bcur[t], cnt[t]);
    __syncthreads();
    if (e0 < NE) {
        int b = d0 >> BSH; int o = atomicAdd(&off[b], 1);
        partA[base[b] + o] = epack(src[e0], d0, e0);
    }
    if (e0 + 512 < NE) {
        int b = d1 >> BSH; int o = atomicAdd(&off[b], 1);
        partA[base[b] + o] = epack(src[e0 + 512], d1, e0 + 512);
    }
    if (e0 + 1024 < NE) {
        int b = d2 >> BSH; int o = atomicAdd(&off[b], 1);
        partA[base[b] + o] = epack(src[e0 + 1024], d2, e0 + 1024);
    }
    if (e0 + 1536 < NE) {
        int b = d3 >> BSH; int o = atomicAdd(&off[b], 1);
        partA[base[b] + o] = epack(src[e0 + 1536], d3, e0 + 1536);
    }
}

// ---------------- pass B: local degree+scan, CSR placement, fused g1 compute --------
// 391 blocks x 512 threads; 256-wide scan; ~65KB store window per bucket.

__global__ __launch_bounds__(512) void k_partB2(const int* __restrict__ bbase,
                                                const u64* __restrict__ partA,
                                                u64* __restrict__ ecsr,
                                                int* __restrict__ ptr,
                                                float* __restrict__ dinv,
                                                const float* __restrict__ x,
                                                const float* __restrict__ W1,
                                                __half* __restrict__ g1) {
    __shared__ int cnt[256], sc[256], cur[256];
    __shared__ float w1[4 * HH];
    int b = blockIdx.x, tid = threadIdx.x;
    if (tid < 4 * HH) w1[tid] = W1[tid];        // 256 threads load W1
    int nd0 = b << BSH;
    int nnode = NN - nd0; if (nnode > 256) nnode = 256;
    if (tid < 256) cnt[tid] = 0;
    __syncthreads();
    int pbeg = bbase[b], pend = bbase[b + 1];
    for (int p = pbeg + tid; p < pend; p += 512)
        atomicAdd(&cnt[edst(partA[p]) - nd0], 1);
    __syncthreads();
    if (tid < 256) sc[tid] = cnt[tid];
    __syncthreads();
    for (int off = 1; off < 256; off <<= 1) {
        int t = (tid < 256 && tid >= off) ? sc[tid - off] : 0;
        __syncthreads();
        if (tid < 256) sc[tid] += t;
        __syncthreads();
    }
    if (tid < nnode) {
        int p = pbeg + sc[tid] - cnt[tid];           // exclusive prefix
        ptr[nd0 + tid] = p;
        cur[tid] = p;
        dinv[nd0 + tid] = rsqrtf((float)(cnt[tid] + 1));
    }
    if (b == NBUK - 1 && tid == 0) ptr[NN] = NE;     // CSR sentinel
    __syncthreads();
    for (int p = pbeg + tid; p < pend; p += 512) {
        u64 t = partA[p];
        int pos = atomicAdd(&cur[edst(t) - nd0], 1);
        ecsr[pos] = t;
    }
    // fused g1 = fp16((x@W1)*dinv): reads cnt/w1 (stable since scan barrier)
    int total = nnode * HH;
    for (int i = tid; i < total; i += 512) {
        int ln = i >> 6, ch = i & 63;
        int node = nd0 + ln;
        float4 xv = *reinterpret_cast<const float4*>(&x[node * 4]);  // lane-broadcast
        float dv = rsqrtf((float)(cnt[ln] + 1));
        float s = fmaf(xv.x, w1[ch],
                  fmaf(xv.y, w1[HH + ch],
                  fmaf(xv.z, w1[2 * HH + ch],
                       xv.w * w1[3 * HH + ch])));
        g1[node * HH + ch] = __float2half(s * dv);
    }
}

// ---------------- aggregation: h[i] = relu(dinv[i]*(g[i] + sum g[src]) + b) ---------
// fp16 g rows (128B), f32 accumulate, fp16 h out; 16 wave-uniform gathers in flight.

__global__ void k_agg(const __half* __restrict__ g, const float* __restrict__ dinv,
                      const int* __restrict__ ptr, const u64* __restrict__ ecsr,
                      const float* __restrict__ bias, __half* __restrict__ h) {
    int node = blockIdx.x * 4 + (threadIdx.x >> 6);  // 4 waves/block, 1 node/wave
    int lane = threadIdx.x & 63;
    if (node >= NN) return;
    float acc = __half2float(g[node * HH + lane]);   // self-loop term
    int e0 = ptr[node], e1 = ptr[node + 1];
    int deg = e1 - e0;
    int lim = deg < 64 ? deg : 64;
    int c = (lane < deg) ? esrc(ecsr[e0 + lane]) : 0;  // coalesced 8B index prefetch
    int j = 0;
    for (; j + 16 <= lim; j += 16) {
        int s0 = __builtin_amdgcn_readlane(c, j);
        int s1 = __builtin_amdgcn_readlane(c, j + 1);
        int s2 = __builtin_amdgcn_readlane(c, j + 2);
        int s3 = __builtin_amdgcn_readlane(c, j + 3);
        int s4 = __builtin_amdgcn_readlane(c, j + 4);
        int s5 = __builtin_amdgcn_readlane(c, j + 5);
        int s6 = __builtin_amdgcn_readlane(c, j + 6);
        int s7 = __builtin_amdgcn_readlane(c, j + 7);
        int s8 = __builtin_amdgcn_readlane(c, j + 8);
        int s9 = __builtin_amdgcn_readlane(c, j + 9);
        int sa = __builtin_amdgcn_readlane(c, j + 10);
        int sb = __builtin_amdgcn_readlane(c, j + 11);
        int sc = __builtin_amdgcn_readlane(c, j + 12);
        int sd = __builtin_amdgcn_readlane(c, j + 13);
        int se = __builtin_amdgcn_readlane(c, j + 14);
        int sf = __builtin_amdgcn_readlane(c, j + 15);
        __half a0 = g[s0 * HH + lane];
        __half a1 = g[s1 * HH + lane];
        __half a2 = g[s2 * HH + lane];
        __half a3 = g[s3 * HH + lane];
        __half a4 = g[s4 * HH + lane];
        __half a5 = g[s5 * HH + lane];
        __half a6 = g[s6 * HH + lane];
        __half a7 = g[s7 * HH + lane];
        __half a8 = g[s8 * HH + lane];
        __half a9 = g[s9 * HH + lane];
        __half aa = g[sa * HH + lane];
        __half ab = g[sb * HH + lane];
        __half ac = g[sc * HH + lane];
        __half ad = g[sd * HH + lane];
        __half ae = g[se * HH + lane];
        __half af = g[sf * HH + lane];
        acc += ((__half2float(a0) + __half2float(a1)) + (__half2float(a2) + __half2float(a3)))
             + ((__half2float(a4) + __half2float(a5)) + (__half2float(a6) + __half2float(a7)));
        acc += ((__half2float(a8) + __half2float(a9)) + (__half2float(aa) + __half2float(ab)))
             + ((__half2float(ac) + __half2float(ad)) + (__half2float(ae) + __half2float(af)));
    }
    for (; j + 4 <= lim; j += 4) {
        int s0 = __builtin_amdgcn_readlane(c, j);
        int s1 = __builtin_amdgcn_readlane(c, j + 1);
        int s2 = __builtin_amdgcn_readlane(c, j + 2);
        int s3 = __builtin_amdgcn_readlane(c, j + 3);
        __half a0 = g[s0 * HH + lane];
        __half a1 = g[s1 * HH + lane];
        __half a2 = g[s2 * HH + lane];
        __half a3 = g[s3 * HH + lane];
        acc += (__half2float(a0) + __half2float(a1)) + (__half2float(a2) + __half2float(a3));
    }
    for (; j < lim; ++j) {
        int s = __builtin_amdgcn_readlane(c, j);
        acc += __half2float(g[s * HH + lane]);
    }
    for (int e = e0 + 64; e < e1; ++e) {             // rare deg>64 tail
        acc += __half2float(g[esrc(ecsr[e]) * HH + lane]);
    }
    h[node * HH + lane] = __float2half(fmaxf(fmaf(acc, dinv[node], bias[lane]), 0.f));
}

// ---------------- 64x64 per-node matmul: out = (in @ W) * dinv  (fp16 in/out) -------

__global__ void k_mm2(const __half* __restrict__ in, const float* __restrict__ W,
                      const float* __restrict__ dinv, __half* __restrict__ out) {
    __shared__ float w[HH * HH];                     // 16 KB
    __shared__ float row[16][HH + 4];                // padded: breaks 4-way bank conflict
    for (int t = threadIdx.x; t < HH * HH; t += 256) w[t] = W[t];
    {
        int flat = threadIdx.x * 4;                  // stage 16 rows (coalesced 8B fp16)
        int r = flat >> 6, c = flat & 63;
        int node = blockIdx.x * 16 + r;
        uint2 v = *reinterpret_cast<const uint2*>(&in[node * HH + c]);
        float2 lo = __half22float2(*reinterpret_cast<__half2*>(&v.x));
        float2 hi = __half22float2(*reinterpret_cast<__half2*>(&v.y));
        row[r][c] = lo.x; row[r][c + 1] = lo.y; row[r][c + 2] = hi.x; row[r][c + 3] = hi.y;
    }
    __syncthreads();
    int r = threadIdx.x >> 4;
    int cg = (threadIdx.x & 15) * 4;
    int node = blockIdx.x * 16 + r;                  // NN%16==0 -> always valid
    float4 acc = {0.f, 0.f, 0.f, 0.f};
    #pragma unroll
    for (int k = 0; k < HH; ++k) {
        float rk = row[r][k];
        float4 wv = *reinterpret_cast<const float4*>(&w[k * HH + cg]);
        acc.x = fmaf(rk, wv.x, acc.x);
        acc.y = fmaf(rk, wv.y, acc.y);
        acc.z = fmaf(rk, wv.z, acc.z);
        acc.w = fmaf(rk, wv.w, acc.w);
    }
    float dv = dinv[node];
    __half2 h01 = __floats2half2_rn(acc.x * dv, acc.y * dv);
    __half2 h23 = __floats2half2_rn(acc.z * dv, acc.w * dv);
    *reinterpret_cast<__half2*>(&out[node * HH + cg])     = h01;
    *reinterpret_cast<__half2*>(&out[node * HH + cg + 2]) = h23;
}

// ---------------- per-node link-pred projections (fp16 in, fp16 out) ----------------

__global__ void k_proj(const __half* __restrict__ h, const float* __restrict__ lpW1,
                       const float* __restrict__ lpb1,
                       __half* __restrict__ A, __half* __restrict__ B) {
    __shared__ float w[128 * HH];                    // 32 KB
    __shared__ float row[16][HH + 4];
    for (int t = threadIdx.x; t < 128 * HH; t += 256) w[t] = lpW1[t];
    {
        int flat = threadIdx.x * 4;
        int r = flat >> 6, c = flat & 63;
        int node = blockIdx.x * 16 + r;
        uint2 v = *reinterpret_cast<const uint2*>(&h[node * HH + c]);
        float2 lo = __half22float2(*reinterpret_cast<__half2*>(&v.x));
        float2 hi = __half22float2(*reinterpret_cast<__half2*>(&v.y));
        row[r][c] = lo.x; row[r][c + 1] = lo.y; row[r][c + 2] = hi.x; row[r][c + 3] = hi.y;
    }
    __syncthreads();
    int r = threadIdx.x >> 4;
    int cg = (threadIdx.x & 15) * 4;
    int node = blockIdx.x * 16 + r;
    float4 acca = *reinterpret_cast<const float4*>(&lpb1[cg]);  // fold bias
    float4 accb = {0.f, 0.f, 0.f, 0.f};
    #pragma unroll
    for (int k = 0; k < HH; ++k) {
        float rk = row[r][k];
        float4 wa = *reinterpret_cast<const float4*>(&w[k * HH + cg]);
        float4 wb = *reinterpret_cast<const float4*>(&w[(HH + k) * HH + cg]);
        acca.x = fmaf(rk, wa.x, acca.x);
        acca.y = fmaf(rk, wa.y, acca.y);
        acca.z = fmaf(rk, wa.z, acca.z);
        acca.w = fmaf(rk, wa.w, acca.w);
        accb.x = fmaf(rk, wb.x, accb.x);
        accb.y = fmaf(rk, wb.y, accb.y);
        accb.z = fmaf(rk, wb.z, accb.z);
        accb.w = fmaf(rk, wb.w, accb.w);
    }
    __half2 a01 = __floats2half2_rn(acca.x, acca.y);
    __half2 a23 = __floats2half2_rn(acca.z, acca.w);
    __half2 b01 = __floats2half2_rn(accb.x, accb.y);
    __half2 b23 = __floats2half2_rn(accb.z, accb.w);
    *reinterpret_cast<__half2*>(&A[node * HH + cg])     = a01;
    *reinterpret_cast<__half2*>(&A[node * HH + cg + 2]) = a23;
    *reinterpret_cast<__half2*>(&B[node * HH + cg])     = b01;
    *reinterpret_cast<__half2*>(&B[node * HH + cg + 2]) = b23;
}

// ---------------- edge scoring: 4-lane cooperative rows (TA-friendly) ----------------

__device__ inline void acc8(float& acc, float4 av, float4 bv, const float* w8) {
    const __half2* ah = reinterpret_cast<const __half2*>(&av);
    const __half2* bh = reinterpret_cast<const __half2*>(&bv);
    #pragma unroll
    for (int i = 0; i < 4; ++i) {
        float2 a = __half22float2(ah[i]);
        float2 b = __half22float2(bh[i]);
        acc = fmaf(fmaxf(a.x + b.x, 0.f), w8[2 * i],     acc);
        acc = fmaf(fmaxf(a.y + b.y, 0.f), w8[2 * i + 1], acc);
    }
}

__global__ void k_edge(const u64* __restrict__ ecsr,
                       const __half* __restrict__ A, const __half* __restrict__ B,
                       const float* __restrict__ lpW2, const float* __restrict__ lpb2,
                       float* __restrict__ out) {
    __shared__ float w[HH];
    if (threadIdx.x < HH) w[threadIdx.x] = lpW2[threadIdx.x];
    __syncthreads();
    int lane = threadIdx.x & 63;
    int wv   = threadIdx.x >> 6;
    int sub  = lane & 3;                             // position within quad
    int g    = lane >> 2;                            // quad id 0..15
    int base = (blockIdx.x * 4 + wv) * 32;           // 32 edges per wave; NE%128==0
    u64 t0 = ecsr[base + g];
    u64 t1 = ecsr[base + 16 + g];
    const float4* pa0 = reinterpret_cast<const float4*>(&A[esrc(t0) * HH]) + sub * 2;
    const float4* pb0 = reinterpret_cast<const float4*>(&B[edst(t0) * HH]) + sub * 2;
    const float4* pa1 = reinterpret_cast<const float4*>(&A[esrc(t1) * HH]) + sub * 2;
    const float4* pb1 = reinterpret_cast<const float4*>(&B[edst(t1) * HH]) + sub * 2;
    float4 a00 = pa0[0], a01 = pa0[1];               // lane covers 32B (16 channels)
    float4 b00 = pb0[0], b01 = pb0[1];
    float4 a10 = pa1[0], a11 = pa1[1];
    float4 b10 = pb1[0], b11 = pb1[1];
    const float* w16 = &w[sub * 16];
    float acc0 = 0.f, acc1 = 0.f;
    acc8(acc0, a00, b00, w16);
    acc8(acc0, a01, b01, w16 + 8);
    acc8(acc1, a10, b10, w16);
    acc8(acc1, a11, b11, w16 + 8);
    acc0 += __shfl_xor(acc0, 1);                     // reduce across quad
    acc0 += __shfl_xor(acc0, 2);
    acc1 += __shfl_xor(acc1, 1);
    acc1 += __shfl_xor(acc1, 2);
    if (sub == 0) {
        float c0 = lpb2[0];
        out[eeid(t0)] = acc0 + c0;                   // scattered 4B stores (L2-merged)
        out[eeid(t1)] = acc1 + c0;
    }
}

// ---------------- launch ----------------

extern "C" void kernel_launch(void* const* d_in, const int* in_sizes, int n_in,
                              void* d_out, int out_size, void* d_ws, size_t ws_size,
                              hipStream_t stream) {
    const float* x    = (const float*)d_in[0];
    const int*   ei   = (const int*)d_in[1];
    const float* W1   = (const float*)d_in[2];
    const float* b1   = (const float*)d_in[3];
    const float* W2   = (const float*)d_in[4];
    const float* b2   = (const float*)d_in[5];
    const float* lpW1 = (const float*)d_in[6];
    const float* lpb1 = (const float*)d_in[7];
    const float* lpW2 = (const float*)d_in[8];
    const float* lpb2 = (const float*)d_in[9];
    const int* src = ei;
    const int* dst = ei + NE;
    float* logits = (float*)d_out;

    // workspace layout (256B aligned slots)
    // lifetimes: bufA = partA(u64) -> g2h -> Bh ; bufB = g1h -> h2 ; bufC = h1 -> Ah
    char* ws = (char*)d_ws;
    size_t o = 0;
    auto take = [&](size_t bytes) { void* p = ws + o; o = (o + bytes + 255) & ~(size_t)255; return p; };
    float*  dinv   = (float*) take(NN * sizeof(float));
    int*    ptr    = (int*)   take((NN + 1) * sizeof(int));
    int*    bcnt   = (int*)   take(NBUK * sizeof(int));
    int*    bbase  = (int*)   take((NBUK + 1) * sizeof(int));
    int*    bcur   = (int*)   take(NBUK * sizeof(int));
    u64*    ecsr   = (u64*)   take((size_t)NE * sizeof(u64));
    char*   bufA   = (char*)  take((size_t)NE * sizeof(u64));
    __half* bufB   = (__half*)take((size_t)NN * HH * sizeof(__half));
    __half* bufC   = (__half*)take((size_t)NN * HH * sizeof(__half));
    u64*    partA  = (u64*)bufA;
    __half* g2h    = (__half*)bufA;
    __half* Bh     = (__half*)bufA;
    __half* g1h    = bufB;
    __half* h2     = bufB;
    __half* h1     = bufC;
    __half* Ah     = bufC;

    hipMemsetAsync(bcnt, 0, NBUK * sizeof(int), stream);
    k_bhist<<<(NE + 2047) / 2048, 512, 0, stream>>>(dst, bcnt);
    k_bscan<<<1, 512, 0, stream>>>(bcnt, bbase, bcur);
    k_partA<<<(NE + 2047) / 2048, 512, 0, stream>>>(src, dst, bcur, partA);
    // partB2: CSR placement + ptr/dinv + fused g1 = fp16((x@W1)*dinv)
    k_partB2<<<NBUK, 512, 0, stream>>>(bbase, partA, ecsr, ptr, dinv, x, W1, g1h);

    // layer 1 aggregation: h1 = fp16(relu(agg(g1) + b1))
    k_agg<<<(NN + 3) / 4, 256, 0, stream>>>(g1h, dinv, ptr, ecsr, b1, h1);

    // layer 2: g2h = fp16((h1@W2)*dinv) (over partA, dead) ; h2 over g1h (dead)
    k_mm2<<<NN / 16, 256, 0, stream>>>(h1, W2, dinv, g2h);
    k_agg<<<(NN + 3) / 4, 256, 0, stream>>>(g2h, dinv, ptr, ecsr, b2, h2);

    // link-pred node projections: Ah over h1 (dead), Bh over g2h (dead)
    k_proj<<<NN / 16, 256, 0, stream>>>(h2, lpW1, lpb1, Ah, Bh);

    // edge scoring: 4-lane cooperative, 128 edges/block
    k_edge<<<NE / 128, 256, 0, stream>>>(ecsr, Ah, Bh, lpW2, lpb2, logits);
}

// Round 14
// 263.575 us; speedup vs baseline: 1.0582x; 1.0582x over previous
//
#include <hip/hip_runtime.h>
#include <hip/hip_fp16.h>

#define NN 100000
#define NE 1600000
#define HH 64
#define BSH 9                 // 512 nodes per bucket (R11-proven; 256 regressed partA chunking)
#define NBUK 196              // ceil(NN / 512)

typedef unsigned long long u64;

// packed edge record: src[16:0] | dst[33:17] | eid[54:34]
__device__ __forceinline__ u64 epack(int s, int d, int e) {
    return (u64)(unsigned)s | ((u64)(unsigned)d << 17) | ((u64)(unsigned)e << 34);
}
__device__ __forceinline__ int esrc(u64 w) { return (int)(w & 0x1FFFF); }
__device__ __forceinline__ int edst(u64 w) { return (int)((w >> 17) & 0x1FFFF); }
__device__ __forceinline__ int eeid(u64 w) { return (int)(w >> 34); }

// ---------------- bucket histogram (per-block LDS, 196 global atomics/block) --------

__global__ __launch_bounds__(1024) void k_bhist(const int* __restrict__ dst,
                                                int* __restrict__ bcnt) {
    __shared__ int cnt[NBUK];
    int tid = threadIdx.x;
    if (tid < NBUK) cnt[tid] = 0;
    __syncthreads();
    int e0 = blockIdx.x * 4096 + tid;
    #pragma unroll
    for (int i = 0; i < 4; ++i) {
        int e = e0 + i * 1024;
        if (e < NE) atomicAdd(&cnt[dst[e] >> BSH], 1);
    }
    __syncthreads();
    if (tid < NBUK && cnt[tid] > 0) atomicAdd(&bcnt[tid], cnt[tid]);
}

// ---------------- bucket scan: 196 -> bases + partA cursors (1 block) ----------------

__global__ void k_bscan(const int* __restrict__ bcnt, int* __restrict__ bbase,
                        int* __restrict__ bcur) {
    __shared__ int sh[256];
    int tid = threadIdx.x;
    int v = (tid < NBUK) ? bcnt[tid] : 0;
    sh[tid] = v;
    __syncthreads();
    for (int off = 1; off < 256; off <<= 1) {
        int t = (tid >= off) ? sh[tid - off] : 0;
        __syncthreads();
        sh[tid] += t;
        __syncthreads();
    }
    if (tid < NBUK) {
        int ex = sh[tid] - v;
        bbase[tid] = ex;
        bcur[tid] = ex;
    }
    if (tid == 0) bbase[NBUK] = NE;
}

// ---------------- pass A: partition edges into 512-node dst-buckets ----------------
// 4096 edges/block -> ~21 records (168B) per (block,bucket) chunk: covers cache
// lines (R13's 2048/391 = 42B chunks re-amplified writes).

__global__ __launch_bounds__(1024) void k_partA(const int* __restrict__ src,
                                                const int* __restrict__ dst,
                                                int* __restrict__ bcur,
                                                u64* __restrict__ partA) {
    __shared__ int cnt[NBUK], off[NBUK], base[NBUK];
    int tid = threadIdx.x;
    if (tid < NBUK) { cnt[tid] = 0; off[tid] = 0; }
    __syncthreads();
    int e0 = blockIdx.x * 4096 + tid;
    int d0 = 0, d1 = 0, d2 = 0, d3 = 0;
    if (e0 < NE)            { d0 = dst[e0];            atomicAdd(&cnt[d0 >> BSH], 1); }
    if (e0 + 1024 < NE)     { d1 = dst[e0 + 1024];     atomicAdd(&cnt[d1 >> BSH], 1); }
    if (e0 + 2048 < NE)     { d2 = dst[e0 + 2048];     atomicAdd(&cnt[d2 >> BSH], 1); }
    if (e0 + 3072 < NE)     { d3 = dst[e0 + 3072];     atomicAdd(&cnt[d3 >> BSH], 1); }
    __syncthreads();
    if (tid < NBUK && cnt[tid] > 0) base[tid] = atomicAdd(&bcur[tid], cnt[tid]);
    __syncthreads();
    if (e0 < NE) {
        int b = d0 >> BSH; int o = atomicAdd(&off[b], 1);
        partA[base[b] + o] = epack(src[e0], d0, e0);
    }
    if (e0 + 1024 < NE) {
        int b = d1 >> BSH; int o = atomicAdd(&off[b], 1);
        partA[base[b] + o] = epack(src[e0 + 1024], d1, e0 + 1024);
    }
    if (e0 + 2048 < NE) {
        int b = d2 >> BSH; int o = atomicAdd(&off[b], 1);
        partA[base[b] + o] = epack(src[e0 + 2048], d2, e0 + 2048);
    }
    if (e0 + 3072 < NE) {
        int b = d3 >> BSH; int o = atomicAdd(&off[b], 1);
        partA[base[b] + o] = epack(src[e0 + 3072], d3, e0 + 3072);
    }
}

// ---------------- pass B: local degree+scan, CSR placement, fused g1 compute --------
// R11 geometry (196 blocks x 1024 thr, 512-node buckets) + R12's mm1 fusion WITHOUT
// scsr (the second scattered stream was R12's regression). g1 writes are dense.

__global__ __launch_bounds__(1024) void k_partB2(const int* __restrict__ bbase,
                                                 const u64* __restrict__ partA,
                                                 u64* __restrict__ ecsr,
                                                 int* __restrict__ ptr,
                                                 float* __restrict__ dinv,
                                                 const float* __restrict__ x,
                                                 const float* __restrict__ W1,
                                                 __half* __restrict__ g1) {
    __shared__ int cnt[512], sc[512], cur[512];
    __shared__ float w1[4 * HH];
    int b = blockIdx.x, tid = threadIdx.x;
    if (tid < 4 * HH) w1[tid] = W1[tid];
    int nd0 = b << BSH;
    int nnode = NN - nd0; if (nnode > 512) nnode = 512;
    if (tid < 512) cnt[tid] = 0;
    __syncthreads();
    int pbeg = bbase[b], pend = bbase[b + 1];
    for (int p = pbeg + tid; p < pend; p += 1024)
        atomicAdd(&cnt[edst(partA[p]) - nd0], 1);
    __syncthreads();
    if (tid < 512) sc[tid] = cnt[tid];
    __syncthreads();
    for (int off = 1; off < 512; off <<= 1) {
        int t = (tid < 512 && tid >= off) ? sc[tid - off] : 0;
        __syncthreads();
        if (tid < 512) sc[tid] += t;
        __syncthreads();
    }
    if (tid < nnode) {
        int p = pbeg + sc[tid] - cnt[tid];           // exclusive prefix
        ptr[nd0 + tid] = p;
        cur[tid] = p;
        dinv[nd0 + tid] = rsqrtf((float)(cnt[tid] + 1));
    }
    if (b == NBUK - 1 && tid == 0) ptr[NN] = NE;     // CSR sentinel
    __syncthreads();
    for (int p = pbeg + tid; p < pend; p += 1024) {
        u64 t = partA[p];
        int pos = atomicAdd(&cur[edst(t) - nd0], 1);
        ecsr[pos] = t;
    }
    // fused g1 = fp16((x@W1)*dinv): reads cnt/w1 (stable since scan barrier);
    // 64 consecutive tids share a node -> x row is a wave-broadcast 16B load;
    // g1 stores are dense coalesced 2B (full-line coverage per wave).
    int total = nnode * HH;
    for (int i = tid; i < total; i += 1024) {
        int ln = i >> 6, ch = i & 63;
        int node = nd0 + ln;
        float4 xv = *reinterpret_cast<const float4*>(&x[node * 4]);
        float dv = rsqrtf((float)(cnt[ln] + 1));
        float s = fmaf(xv.x, w1[ch],
                  fmaf(xv.y, w1[HH + ch],
                  fmaf(xv.z, w1[2 * HH + ch],
                       xv.w * w1[3 * HH + ch])));
        g1[node * HH + ch] = __float2half(s * dv);
    }
}

// ---------------- aggregation: h[i] = relu(dinv[i]*(g[i] + sum g[src]) + b) ---------
// fp16 g rows (128B), f32 accumulate, fp16 h out; 16 wave-uniform gathers in flight.

__global__ void k_agg(const __half* __restrict__ g, const float* __restrict__ dinv,
                      const int* __restrict__ ptr, const u64* __restrict__ ecsr,
                      const float* __restrict__ bias, __half* __restrict__ h) {
    int node = blockIdx.x * 4 + (threadIdx.x >> 6);  // 4 waves/block, 1 node/wave
    int lane = threadIdx.x & 63;
    if (node >= NN) return;
    float acc = __half2float(g[node * HH + lane]);   // self-loop term
    int e0 = ptr[node], e1 = ptr[node + 1];
    int deg = e1 - e0;
    int lim = deg < 64 ? deg : 64;
    int c = (lane < deg) ? esrc(ecsr[e0 + lane]) : 0;  // coalesced 8B index prefetch
    int j = 0;
    for (; j + 16 <= lim; j += 16) {
        int s0 = __builtin_amdgcn_readlane(c, j);
        int s1 = __builtin_amdgcn_readlane(c, j + 1);
        int s2 = __builtin_amdgcn_readlane(c, j + 2);
        int s3 = __builtin_amdgcn_readlane(c, j + 3);
        int s4 = __builtin_amdgcn_readlane(c, j + 4);
        int s5 = __builtin_amdgcn_readlane(c, j + 5);
        int s6 = __builtin_amdgcn_readlane(c, j + 6);
        int s7 = __builtin_amdgcn_readlane(c, j + 7);
        int s8 = __builtin_amdgcn_readlane(c, j + 8);
        int s9 = __builtin_amdgcn_readlane(c, j + 9);
        int sa = __builtin_amdgcn_readlane(c, j + 10);
        int sb = __builtin_amdgcn_readlane(c, j + 11);
        int sc = __builtin_amdgcn_readlane(c, j + 12);
        int sd = __builtin_amdgcn_readlane(c, j + 13);
        int se = __builtin_amdgcn_readlane(c, j + 14);
        int sf = __builtin_amdgcn_readlane(c, j + 15);
        __half a0 = g[s0 * HH + lane];
        __half a1 = g[s1 * HH + lane];
        __half a2 = g[s2 * HH + lane];
        __half a3 = g[s3 * HH + lane];
        __half a4 = g[s4 * HH + lane];
        __half a5 = g[s5 * HH + lane];
        __half a6 = g[s6 * HH + lane];
        __half a7 = g[s7 * HH + lane];
        __half a8 = g[s8 * HH + lane];
        __half a9 = g[s9 * HH + lane];
        __half aa = g[sa * HH + lane];
        __half ab = g[sb * HH + lane];
        __half ac = g[sc * HH + lane];
        __half ad = g[sd * HH + lane];
        __half ae = g[se * HH + lane];
        __half af = g[sf * HH + lane];
        acc += ((__half2float(a0) + __half2float(a1)) + (__half2float(a2) + __half2float(a3)))
             + ((__half2float(a4) + __half2float(a5)) + (__half2float(a6) + __half2float(a7)));
        acc += ((__half2float(a8) + __half2float(a9)) + (__half2float(aa) + __half2float(ab)))
             + ((__half2float(ac) + __half2float(ad)) + (__half2float(ae) + __half2float(af)));
    }
    for (; j + 4 <= lim; j += 4) {
        int s0 = __builtin_amdgcn_readlane(c, j);
        int s1 = __builtin_amdgcn_readlane(c, j + 1);
        int s2 = __builtin_amdgcn_readlane(c, j + 2);
        int s3 = __builtin_amdgcn_readlane(c, j + 3);
        __half a0 = g[s0 * HH + lane];
        __half a1 = g[s1 * HH + lane];
        __half a2 = g[s2 * HH + lane];
        __half a3 = g[s3 * HH + lane];
        acc += (__half2float(a0) + __half2float(a1)) + (__half2float(a2) + __half2float(a3));
    }
    for (; j < lim; ++j) {
        int s = __builtin_amdgcn_readlane(c, j);
        acc += __half2float(g[s * HH + lane]);
    }
    for (int e = e0 + 64; e < e1; ++e) {             // rare deg>64 tail
        acc += __half2float(g[esrc(ecsr[e]) * HH + lane]);
    }
    h[node * HH + lane] = __float2half(fmaxf(fmaf(acc, dinv[node], bias[lane]), 0.f));
}

// ---------------- 64x64 per-node matmul: out = (in @ W) * dinv  (fp16 in/out) -------

__global__ void k_mm2(const __half* __restrict__ in, const float* __restrict__ W,
                      const float* __restrict__ dinv, __half* __restrict__ out) {
    __shared__ float w[HH * HH];                     // 16 KB
    __shared__ float row[16][HH + 4];                // padded: breaks 4-way bank conflict
    for (int t = threadIdx.x; t < HH * HH; t += 256) w[t] = W[t];
    {
        int flat = threadIdx.x * 4;                  // stage 16 rows (coalesced 8B fp16)
        int r = flat >> 6, c = flat & 63;
        int node = blockIdx.x * 16 + r;
        uint2 v = *reinterpret_cast<const uint2*>(&in[node * HH + c]);
        float2 lo = __half22float2(*reinterpret_cast<__half2*>(&v.x));
        float2 hi = __half22float2(*reinterpret_cast<__half2*>(&v.y));
        row[r][c] = lo.x; row[r][c + 1] = lo.y; row[r][c + 2] = hi.x; row[r][c + 3] = hi.y;
    }
    __syncthreads();
    int r = threadIdx.x >> 4;
    int cg = (threadIdx.x & 15) * 4;
    int node = blockIdx.x * 16 + r;                  // NN%16==0 -> always valid
    float4 acc = {0.f, 0.f, 0.f, 0.f};
    #pragma unroll
    for (int k = 0; k < HH; ++k) {
        float rk = row[r][k];
        float4 wv = *reinterpret_cast<const float4*>(&w[k * HH + cg]);
        acc.x = fmaf(rk, wv.x, acc.x);
        acc.y = fmaf(rk, wv.y, acc.y);
        acc.z = fmaf(rk, wv.z, acc.z);
        acc.w = fmaf(rk, wv.w, acc.w);
    }
    float dv = dinv[node];
    __half2 h01 = __floats2half2_rn(acc.x * dv, acc.y * dv);
    __half2 h23 = __floats2half2_rn(acc.z * dv, acc.w * dv);
    *reinterpret_cast<__half2*>(&out[node * HH + cg])     = h01;
    *reinterpret_cast<__half2*>(&out[node * HH + cg + 2]) = h23;
}

// ---------------- per-node link-pred projections (fp16 in, fp16 out) ----------------

__global__ void k_proj(const __half* __restrict__ h, const float* __restrict__ lpW1,
                       const float* __restrict__ lpb1,
                       __half* __restrict__ A, __half* __restrict__ B) {
    __shared__ float w[128 * HH];                    // 32 KB
    __shared__ float row[16][HH + 4];
    for (int t = threadIdx.x; t < 128 * HH; t += 256) w[t] = lpW1[t];
    {
        int flat = threadIdx.x * 4;
        int r = flat >> 6, c = flat & 63;
        int node = blockIdx.x * 16 + r;
        uint2 v = *reinterpret_cast<const uint2*>(&h[node * HH + c]);
        float2 lo = __half22float2(*reinterpret_cast<__half2*>(&v.x));
        float2 hi = __half22float2(*reinterpret_cast<__half2*>(&v.y));
        row[r][c] = lo.x; row[r][c + 1] = lo.y; row[r][c + 2] = hi.x; row[r][c + 3] = hi.y;
    }
    __syncthreads();
    int r = threadIdx.x >> 4;
    int cg = (threadIdx.x & 15) * 4;
    int node = blockIdx.x * 16 + r;
    float4 acca = *reinterpret_cast<const float4*>(&lpb1[cg]);  // fold bias
    float4 accb = {0.f, 0.f, 0.f, 0.f};
    #pragma unroll
    for (int k = 0; k < HH; ++k) {
        float rk = row[r][k];
        float4 wa = *reinterpret_cast<const float4*>(&w[k * HH + cg]);
        float4 wb = *reinterpret_cast<const float4*>(&w[(HH + k) * HH + cg]);
        acca.x = fmaf(rk, wa.x, acca.x);
        acca.y = fmaf(rk, wa.y, acca.y);
        acca.z = fmaf(rk, wa.z, acca.z);
        acca.w = fmaf(rk, wa.w, acca.w);
        accb.x = fmaf(rk, wb.x, accb.x);
        accb.y = fmaf(rk, wb.y, accb.y);
        accb.z = fmaf(rk, wb.z, accb.z);
        accb.w = fmaf(rk, wb.w, accb.w);
    }
    __half2 a01 = __floats2half2_rn(acca.x, acca.y);
    __half2 a23 = __floats2half2_rn(acca.z, acca.w);
    __half2 b01 = __floats2half2_rn(accb.x, accb.y);
    __half2 b23 = __floats2half2_rn(accb.z, accb.w);
    *reinterpret_cast<__half2*>(&A[node * HH + cg])     = a01;
    *reinterpret_cast<__half2*>(&A[node * HH + cg + 2]) = a23;
    *reinterpret_cast<__half2*>(&B[node * HH + cg])     = b01;
    *reinterpret_cast<__half2*>(&B[node * HH + cg + 2]) = b23;
}

// ---------------- edge scoring: 4-lane cooperative rows (TA-friendly) ----------------

__device__ inline void acc8(float& acc, float4 av, float4 bv, const float* w8) {
    const __half2* ah = reinterpret_cast<const __half2*>(&av);
    const __half2* bh = reinterpret_cast<const __half2*>(&bv);
    #pragma unroll
    for (int i = 0; i < 4; ++i) {
        float2 a = __half22float2(ah[i]);
        float2 b = __half22float2(bh[i]);
        acc = fmaf(fmaxf(a.x + b.x, 0.f), w8[2 * i],     acc);
        acc = fmaf(fmaxf(a.y + b.y, 0.f), w8[2 * i + 1], acc);
    }
}

__global__ void k_edge(const u64* __restrict__ ecsr,
                       const __half* __restrict__ A, const __half* __restrict__ B,
                       const float* __restrict__ lpW2, const float* __restrict__ lpb2,
                       float* __restrict__ out) {
    __shared__ float w[HH];
    if (threadIdx.x < HH) w[threadIdx.x] = lpW2[threadIdx.x];
    __syncthreads();
    int lane = threadIdx.x & 63;
    int wv   = threadIdx.x >> 6;
    int sub  = lane & 3;                             // position within quad
    int g    = lane >> 2;                            // quad id 0..15
    int base = (blockIdx.x * 4 + wv) * 32;           // 32 edges per wave; NE%128==0
    u64 t0 = ecsr[base + g];
    u64 t1 = ecsr[base + 16 + g];
    const float4* pa0 = reinterpret_cast<const float4*>(&A[esrc(t0) * HH]) + sub * 2;
    const float4* pb0 = reinterpret_cast<const float4*>(&B[edst(t0) * HH]) + sub * 2;
    const float4* pa1 = reinterpret_cast<const float4*>(&A[esrc(t1) * HH]) + sub * 2;
    const float4* pb1 = reinterpret_cast<const float4*>(&B[edst(t1) * HH]) + sub * 2;
    float4 a00 = pa0[0], a01 = pa0[1];               // lane covers 32B (16 channels)
    float4 b00 = pb0[0], b01 = pb0[1];
    float4 a10 = pa1[0], a11 = pa1[1];
    float4 b10 = pb1[0], b11 = pb1[1];
    const float* w16 = &w[sub * 16];
    float acc0 = 0.f, acc1 = 0.f;
    acc8(acc0, a00, b00, w16);
    acc8(acc0, a01, b01, w16 + 8);
    acc8(acc1, a10, b10, w16);
    acc8(acc1, a11, b11, w16 + 8);
    acc0 += __shfl_xor(acc0, 1);                     // reduce across quad
    acc0 += __shfl_xor(acc0, 2);
    acc1 += __shfl_xor(acc1, 1);
    acc1 += __shfl_xor(acc1, 2);
    if (sub == 0) {
        float c0 = lpb2[0];
        out[eeid(t0)] = acc0 + c0;                   // scattered 4B stores (L2-merged)
        out[eeid(t1)] = acc1 + c0;
    }
}

// ---------------- launch ----------------

extern "C" void kernel_launch(void* const* d_in, const int* in_sizes, int n_in,
                              void* d_out, int out_size, void* d_ws, size_t ws_size,
                              hipStream_t stream) {
    const float* x    = (const float*)d_in[0];
    const int*   ei   = (const int*)d_in[1];
    const float* W1   = (const float*)d_in[2];
    const float* b1   = (const float*)d_in[3];
    const float* W2   = (const float*)d_in[4];
    const float* b2   = (const float*)d_in[5];
    const float* lpW1 = (const float*)d_in[6];
    const float* lpb1 = (const float*)d_in[7];
    const float* lpW2 = (const float*)d_in[8];
    const float* lpb2 = (const float*)d_in[9];
    const int* src = ei;
    const int* dst = ei + NE;
    float* logits = (float*)d_out;

    // workspace layout (256B aligned slots)
    // lifetimes: bufA = partA(u64) -> g2h -> Bh ; bufB = g1h -> h2 ; bufC = h1 -> Ah
    char* ws = (char*)d_ws;
    size_t o = 0;
    auto take = [&](size_t bytes) { void* p = ws + o; o = (o + bytes + 255) & ~(size_t)255; return p; };
    float*  dinv   = (float*) take(NN * sizeof(float));
    int*    ptr    = (int*)   take((NN + 1) * sizeof(int));
    int*    bcnt   = (int*)   take(NBUK * sizeof(int));
    int*    bbase  = (int*)   take((NBUK + 1) * sizeof(int));
    int*    bcur   = (int*)   take(NBUK * sizeof(int));
    u64*    ecsr   = (u64*)   take((size_t)NE * sizeof(u64));
    char*   bufA   = (char*)  take((size_t)NE * sizeof(u64));
    __half* bufB   = (__half*)take((size_t)NN * HH * sizeof(__half));
    __half* bufC   = (__half*)take((size_t)NN * HH * sizeof(__half));
    u64*    partA  = (u64*)bufA;
    __half* g2h    = (__half*)bufA;
    __half* Bh     = (__half*)bufA;
    __half* g1h    = bufB;
    __half* h2     = bufB;
    __half* h1     = bufC;
    __half* Ah     = bufC;

    hipMemsetAsync(bcnt, 0, NBUK * sizeof(int), stream);
    k_bhist<<<(NE + 4095) / 4096, 1024, 0, stream>>>(dst, bcnt);
    k_bscan<<<1, 256, 0, stream>>>(bcnt, bbase, bcur);
    k_partA<<<(NE + 4095) / 4096, 1024, 0, stream>>>(src, dst, bcur, partA);
    // partB2: CSR placement + ptr/dinv + fused g1 = fp16((x@W1)*dinv)
    k_partB2<<<NBUK, 1024, 0, stream>>>(bbase, partA, ecsr, ptr, dinv, x, W1, g1h);

    // layer 1 aggregation: h1 = fp16(relu(agg(g1) + b1))
    k_agg<<<(NN + 3) / 4, 256, 0, stream>>>(g1h, dinv, ptr, ecsr, b1, h1);

    // layer 2: g2h = fp16((h1@W2)*dinv) (over partA, dead) ; h2 over g1h (dead)
    k_mm2<<<NN / 16, 256, 0, stream>>>(h1, W2, dinv, g2h);
    k_agg<<<(NN + 3) / 4, 256, 0, stream>>>(g2h, dinv, ptr, ecsr, b2, h2);

    // link-pred node projections: Ah over h1 (dead), Bh over g2h (dead)
    k_proj<<<NN / 16, 256, 0, stream>>>(h2, lpW1, lpb1, Ah, Bh);

    // edge scoring: 4-lane cooperative, 128 edges/block
    k_edge<<<NE / 128, 256, 0, stream>>>(ecsr, Ah, Bh, lpW2, lpb2, logits);
}